// Round 1
// baseline (611.327 us; speedup 1.0000x reference)
//
#include <hip/hip_runtime.h>
#include <hip/hip_bf16.h>
#include <float.h>

// Problem constants
constexpr int B  = 64;
constexpr int C  = 256;
constexpr int HW = 1024;   // 32*32
constexpr int K  = 1024;
constexpr int PT = 64;     // positions per block tile
constexpr float BETA = 0.25f;
constexpr float NTOT_INV = 1.0f / 16777216.0f;  // 1 / (64*256*32*32)

// --- kernel 1: e_sq[k] = sum_j emb[k][j]^2 (one wave per code) ---
__global__ __launch_bounds__(256) void esq_kernel(const float* __restrict__ emb,
                                                  float* __restrict__ esq) {
    const int wid  = threadIdx.x >> 6;
    const int lane = threadIdx.x & 63;
    const int k    = blockIdx.x * 4 + wid;
    const float4 v = *(const float4*)(emb + k * C + lane * 4);
    float s = v.x * v.x + v.y * v.y + v.z * v.z + v.w * v.w;
#pragma unroll
    for (int off = 32; off > 0; off >>= 1) s += __shfl_down(s, off, 64);
    if (lane == 0) esq[k] = s;
}

// --- kernel 2: fused GEMM + argmin + gather + write + loss partials ---
// grid: (HW/PT = 16, B = 64); block: 256 threads (16 pos-groups x 16 code-groups)
__global__ __launch_bounds__(256) void vq_main(const float* __restrict__ z,
                                               const float* __restrict__ emb,
                                               const float* __restrict__ esq,
                                               float* __restrict__ out,
                                               float* __restrict__ acc_loss) {
    __shared__ float Zs[16][64];    // [cc][pos]
    __shared__ float EsT[16][64];   // [cc][code]
    __shared__ float redv[16][64];
    __shared__ int   redi[16][64];
    __shared__ int   kmin[64];
    __shared__ float wred[8];

    const int tid  = threadIdx.x;
    const int tx   = tid & 15;   // position group (4 positions)
    const int ty   = tid >> 4;   // code group (4 codes per chunk)
    const int b    = blockIdx.y;
    const int pos0 = blockIdx.x * PT;
    const float* zb = z + (size_t)b * C * HW;

    float best[4] = {FLT_MAX, FLT_MAX, FLT_MAX, FLT_MAX};
    int   bidx[4] = {0, 0, 0, 0};

    // staging index split
    const int z_cc = tid >> 4, z_pq = tid & 15;   // Z: 16 rows x 16 float4
    const int e_kk = tid >> 2, e_cq = tid & 3;    // E: 64 rows x 4 float4

    for (int k0 = 0; k0 < K; k0 += 64) {
        float acc[4][4];
#pragma unroll
        for (int j = 0; j < 4; ++j)
#pragma unroll
            for (int i = 0; i < 4; ++i) acc[j][i] = 0.0f;

        for (int c0 = 0; c0 < C; c0 += 16) {
            __syncthreads();
            // stage Z chunk: Zs[cc][p] = z[b][c0+cc][pos0+p]
            float4 zv4 = *(const float4*)(zb + (size_t)(c0 + z_cc) * HW + pos0 + z_pq * 4);
            *(float4*)&Zs[z_cc][z_pq * 4] = zv4;
            // stage E chunk transposed: EsT[cc][kk] = emb[k0+kk][c0+cc]
            float4 ev4 = *(const float4*)(emb + (size_t)(k0 + e_kk) * C + c0 + e_cq * 4);
            EsT[e_cq * 4 + 0][e_kk] = ev4.x;
            EsT[e_cq * 4 + 1][e_kk] = ev4.y;
            EsT[e_cq * 4 + 2][e_kk] = ev4.z;
            EsT[e_cq * 4 + 3][e_kk] = ev4.w;
            __syncthreads();
#pragma unroll
            for (int cc = 0; cc < 16; ++cc) {
                float4 zr = *(const float4*)&Zs[cc][tx * 4];
                float4 er = *(const float4*)&EsT[cc][ty * 4];
                float zz[4] = {zr.x, zr.y, zr.z, zr.w};
                float ee[4] = {er.x, er.y, er.z, er.w};
#pragma unroll
                for (int j = 0; j < 4; ++j)
#pragma unroll
                    for (int i = 0; i < 4; ++i)
                        acc[j][i] = fmaf(ee[j], zz[i], acc[j][i]);
            }
        }
        // distances for this code chunk; keep running min (lowest index on tie)
#pragma unroll
        for (int j = 0; j < 4; ++j) {
            const int k = k0 + ty * 4 + j;
            const float eq = esq[k];
#pragma unroll
            for (int i = 0; i < 4; ++i) {
                float d = fmaf(-2.0f, acc[j][i], eq);
                if (d < best[i]) { best[i] = d; bidx[i] = k; }
            }
        }
    }

    // cross-thread argmin reduction (16 code-groups per position)
#pragma unroll
    for (int i = 0; i < 4; ++i) {
        redv[ty][tx * 4 + i] = best[i];
        redi[ty][tx * 4 + i] = bidx[i];
    }
    __syncthreads();
    if (tid < 64) {
        float v = redv[0][tid];
        int  id = redi[0][tid];
#pragma unroll
        for (int r = 1; r < 16; ++r) {
            float vv = redv[r][tid];
            int   ii = redi[r][tid];
            if (vv < v || (vv == v && ii < id)) { v = vv; id = ii; }
        }
        kmin[tid] = id;
    }
    __syncthreads();

    // epilogue: gather winning code rows, write straight-through output, loss partials
    const int p  = tid & 63;
    const int cq = tid >> 6;
    const int km = kmin[p];
    const float* erow = emb + (size_t)km * C;
    float s_sq = 0.0f, s_d = 0.0f;
    const size_t base = (size_t)b * C * HW + pos0 + p;
    for (int ch = cq; ch < C; ch += 4) {
        float ev = erow[ch];
        float zv = z[base + (size_t)ch * HW];
        float diff = ev - zv;                     // z_q - z
        out[base + (size_t)ch * HW] = zv + diff;  // straight-through fwd value
        s_sq = fmaf(diff, diff, s_sq);
        s_d += diff;
    }
#pragma unroll
    for (int off = 32; off > 0; off >>= 1) {
        s_sq += __shfl_down(s_sq, off, 64);
        s_d  += __shfl_down(s_d,  off, 64);
    }
    const int lane = tid & 63, wv = tid >> 6;
    if (lane == 0) { wred[wv] = s_sq; wred[4 + wv] = s_d; }
    __syncthreads();
    if (tid == 0) {
        float a = wred[0] + wred[1] + wred[2] + wred[3];
        float d = wred[4] + wred[5] + wred[6] + wred[7];
        atomicAdd(&acc_loss[0], a);
        atomicAdd(&acc_loss[1], d);
    }
}

// --- kernel 3: finalize scalar loss ---
__global__ void loss_kernel(const float* __restrict__ acc_loss,
                            float* __restrict__ out_loss) {
    out_loss[0] = acc_loss[0] * NTOT_INV + BETA * (acc_loss[1] * NTOT_INV);
}

extern "C" void kernel_launch(void* const* d_in, const int* in_sizes, int n_in,
                              void* d_out, int out_size, void* d_ws, size_t ws_size,
                              hipStream_t stream) {
    const float* z   = (const float*)d_in[0];   // [64,256,32,32]
    const float* emb = (const float*)d_in[1];   // [1024,256]
    float* out = (float*)d_out;                 // [16777216 z_q] + [1 loss]
    float* ws  = (float*)d_ws;
    float* acc = ws;        // 2 floats: sum_sq_diff, sum_diff
    float* esq = ws + 64;   // 1024 floats

    hipMemsetAsync(acc, 0, 2 * sizeof(float), stream);
    esq_kernel<<<dim3(K / 4), 256, 0, stream>>>(emb, esq);
    vq_main<<<dim3(HW / PT, B), 256, 0, stream>>>(z, emb, esq, out, acc);
    loss_kernel<<<1, 1, 0, stream>>>(acc, out + (size_t)B * C * HW);
}

// Round 2
// 256.770 us; speedup vs baseline: 2.3808x; 2.3808x over previous
//
#include <hip/hip_runtime.h>
#include <hip/hip_bf16.h>
#include <float.h>

// Problem constants
constexpr int B  = 64;
constexpr int C  = 256;
constexpr int HW = 1024;   // 32*32
constexpr int K  = 1024;
constexpr float BETA = 0.25f;
constexpr float NTOT_INV = 1.0f / 16777216.0f;  // 1 / (64*256*32*32)

typedef __attribute__((ext_vector_type(8))) short bf16x8;
typedef __attribute__((ext_vector_type(4))) float floatx4;

#define AS1 __attribute__((address_space(1)))
#define AS3 __attribute__((address_space(3)))

__device__ inline unsigned short f2bf(float x) {
    unsigned u = __float_as_uint(x);
    return (unsigned short)((u + 0x7FFFu + ((u >> 16) & 1u)) >> 16);  // RNE
}

// --- kernel 1: emb fp32 -> bf16 (row-major) + esq1[k] = 1 + ||e_k||^2 ---
// one wave per code; grid 256 x 256 threads
__global__ __launch_bounds__(256) void prep_kernel(const float* __restrict__ emb,
                                                   short* __restrict__ emb_bf,
                                                   float* __restrict__ esq1) {
    const int wid  = threadIdx.x >> 6;
    const int lane = threadIdx.x & 63;
    const int k    = blockIdx.x * 4 + wid;
    const float4 v = *(const float4*)(emb + (size_t)k * C + lane * 4);
    ushort4 pk = { f2bf(v.x), f2bf(v.y), f2bf(v.z), f2bf(v.w) };
    *(ushort4*)(emb_bf + (size_t)k * C + lane * 4) = pk;
    float s = v.x * v.x + v.y * v.y + v.z * v.z + v.w * v.w;
#pragma unroll
    for (int off = 32; off > 0; off >>= 1) s += __shfl_down(s, off, 64);
    if (lane == 0) esq1[k] = 1.0f + s;
}

// --- kernel 2: MFMA GEMM distances + argmin + gather + out + loss partials ---
// grid: 1024 blocks (64 tokens each); block: 256 threads = 4 waves
__global__ __launch_bounds__(256) void vq_main(const float* __restrict__ z,
                                               const float* __restrict__ emb,
                                               const short* __restrict__ emb_bf,
                                               const float* __restrict__ esq1,
                                               float* __restrict__ out,
                                               float* __restrict__ acc_loss) {
    // blocked LDS layouts: [32 ch-blocks][64 rows][8 ch] bf16, 16B-contiguous rows
    __shared__ short Zs[32 * 512];   // rows = tokens
    __shared__ short Es[32 * 512];   // rows = codes (chunk of 64)
    __shared__ int   kmin[64];
    __shared__ float wred[8];

    const int tid = threadIdx.x;
    const int w   = tid >> 6;     // wave id 0..3
    const int L   = tid & 63;     // lane
    const int q   = L >> 4;       // quad
    const int l15 = L & 15;

    const int bidx  = blockIdx.x;
    const int b     = bidx >> 4;          // batch
    const int hw0   = (bidx & 15) * 64;   // position tile base
    const float* zb = z + (size_t)b * C * HW + hw0;

    // ---- stage Z tile once: Zs[cb][tok][8] = bf16(z[b][cb*8+j][hw0+tok]) ----
    {
        const int tt = tid & 63;
        const float* zp = zb + tt;
        for (int cb = tid >> 6; cb < 32; cb += 4) {
            float v[8];
#pragma unroll
            for (int j = 0; j < 8; ++j) v[j] = zp[(size_t)(cb * 8 + j) * HW];
            union { unsigned short s[8]; uint4 u; } pk;
#pragma unroll
            for (int j = 0; j < 8; ++j) pk.s[j] = f2bf(v[j]);
            *(uint4*)&Zs[cb * 512 + tt * 8] = pk.u;
        }
    }

    // frag element offsets (shorts)
    const int zoff = q * 512 + (w * 16 + l15) * 8;  // B: token = w*16+l15
    const int eoff = q * 512 + l15 * 8;             // A: code  = m*16+l15

    unsigned int best = 0xFFFFFFFFu;

    for (int k0 = 0; k0 < K; k0 += 64) {
        __syncthreads();   // previous chunk's readers done (also covers Zs writes, iter 0)
        // ---- stage E chunk via async global->LDS, 16B/lane ----
        {
            const short* gp0 = emb_bf + (size_t)(k0 + L) * C + (w * 8) * 8;
#pragma unroll
            for (int i = 0; i < 8; ++i) {
                __builtin_amdgcn_global_load_lds((const AS1 void*)(gp0 + i * 8),
                                                 (AS3 void*)(&Es[(w * 8 + i) * 512]),
                                                 16, 0, 0);
            }
        }
        __syncthreads();   // barrier drain waits vmcnt(0): Es visible

        floatx4 acc[4];
#pragma unroll
        for (int m = 0; m < 4; ++m) acc[m] = (floatx4){0.f, 0.f, 0.f, 0.f};

#pragma unroll
        for (int c0 = 0; c0 < 256; c0 += 32) {
            const int blk = (c0 >> 3) * 512;
            bf16x8 bfrag = *(const bf16x8*)&Zs[blk + zoff];
#pragma unroll
            for (int m = 0; m < 4; ++m) {
                bf16x8 afrag = *(const bf16x8*)&Es[blk + eoff + m * 128];
                acc[m] = __builtin_amdgcn_mfma_f32_16x16x32_bf16(afrag, bfrag, acc[m], 0, 0, 0);
            }
        }

        // ---- distances + packed argmin (positive floats: bits monotone) ----
#pragma unroll
        for (int m = 0; m < 4; ++m) {
            const float4 eq = *(const float4*)&esq1[k0 + m * 16 + q * 4];
            const float eqa[4] = {eq.x, eq.y, eq.z, eq.w};
#pragma unroll
            for (int r = 0; r < 4; ++r) {
                const int code = k0 + m * 16 + q * 4 + r;
                float d = fmaf(-2.0f, acc[m][r], eqa[r]);
                unsigned int u = (__float_as_uint(d) & 0xFFFFFC00u) | (unsigned int)code;
                best = best < u ? best : u;
            }
        }
    }

    // per-token final argmin: candidates live in lanes L, L^16, L^32, L^48
    {
        unsigned int o = (unsigned int)__shfl_xor((int)best, 16, 64);
        best = best < o ? best : o;
        o = (unsigned int)__shfl_xor((int)best, 32, 64);
        best = best < o ? best : o;
        if (L < 16) kmin[w * 16 + L] = (int)(best & 1023u);
    }
    __syncthreads();

    // ---- epilogue: gather code row (fp32), straight-through out, loss partials ----
    const int p  = tid & 63;
    const int cq = tid >> 6;
    const int km = kmin[p];
    const float* erow = emb + (size_t)km * C;
    float s_sq = 0.0f, s_d = 0.0f;
    const size_t base = (size_t)b * C * HW + hw0 + p;
    for (int ch = cq; ch < C; ch += 4) {
        float ev = erow[ch];
        float zv = z[base + (size_t)ch * HW];
        float diff = ev - zv;                     // z_q - z
        out[base + (size_t)ch * HW] = zv + diff;  // straight-through fwd value
        s_sq = fmaf(diff, diff, s_sq);
        s_d += diff;
    }
#pragma unroll
    for (int off = 32; off > 0; off >>= 1) {
        s_sq += __shfl_down(s_sq, off, 64);
        s_d  += __shfl_down(s_d,  off, 64);
    }
    if (L == 0) { wred[w] = s_sq; wred[4 + w] = s_d; }
    __syncthreads();
    if (tid == 0) {
        float a = wred[0] + wred[1] + wred[2] + wred[3];
        float d = wred[4] + wred[5] + wred[6] + wred[7];
        atomicAdd(&acc_loss[0], a);
        atomicAdd(&acc_loss[1], d);
    }
}

// --- kernel 3: finalize scalar loss ---
__global__ void loss_kernel(const float* __restrict__ acc_loss,
                            float* __restrict__ out_loss) {
    out_loss[0] = acc_loss[0] * NTOT_INV + BETA * (acc_loss[1] * NTOT_INV);
}

extern "C" void kernel_launch(void* const* d_in, const int* in_sizes, int n_in,
                              void* d_out, int out_size, void* d_ws, size_t ws_size,
                              hipStream_t stream) {
    const float* z   = (const float*)d_in[0];   // [64,256,32,32]
    const float* emb = (const float*)d_in[1];   // [1024,256]
    float* out = (float*)d_out;                 // [16777216 z_q] + [1 loss]
    float* ws  = (float*)d_ws;
    float* acc  = ws;                               // 2 floats
    float* esq1 = ws + 64;                          // 1024 floats
    short* emb_bf = (short*)(ws + 64 + 1024);       // 1024*256 bf16 = 512 KB

    hipMemsetAsync(acc, 0, 2 * sizeof(float), stream);
    prep_kernel<<<dim3(K / 4), 256, 0, stream>>>(emb, emb_bf, esq1);
    vq_main<<<dim3(1024), 256, 0, stream>>>(z, emb, emb_bf, esq1, out, acc);
    loss_kernel<<<1, 1, 0, stream>>>(acc, out + (size_t)B * C * HW);
}

// Round 3
// 220.455 us; speedup vs baseline: 2.7730x; 1.1647x over previous
//
#include <hip/hip_runtime.h>
#include <hip/hip_bf16.h>
#include <float.h>

// Problem constants
constexpr int B  = 64;
constexpr int C  = 256;
constexpr int HW = 1024;   // 32*32
constexpr int K  = 1024;
constexpr float BETA = 0.25f;
constexpr float NTOT_INV = 1.0f / 16777216.0f;  // 1 / (64*256*32*32)

typedef __attribute__((ext_vector_type(8))) short bf16x8;
typedef __attribute__((ext_vector_type(4))) float floatx4;

union U16 { uint4 u; bf16x8 b; };

__device__ inline unsigned short f2bf(float x) {
    unsigned u = __float_as_uint(x);
    return (unsigned short)((u + 0x7FFFu + ((u >> 16) & 1u)) >> 16);  // RNE
}

// --- kernel 1: emb fp32 -> bf16 (row-major) + esq1[k] = 1 + ||e_k||^2 ---
// also zeroes the loss accumulators (block 0). grid 256 x 256 threads.
__global__ __launch_bounds__(256) void prep_kernel(const float* __restrict__ emb,
                                                   short* __restrict__ emb_bf,
                                                   float* __restrict__ esq1,
                                                   float* __restrict__ acc_loss) {
    if (blockIdx.x == 0 && threadIdx.x < 2) acc_loss[threadIdx.x] = 0.0f;
    const int wid  = threadIdx.x >> 6;
    const int lane = threadIdx.x & 63;
    const int k    = blockIdx.x * 4 + wid;
    const float4 v = *(const float4*)(emb + (size_t)k * C + lane * 4);
    ushort4 pk = { f2bf(v.x), f2bf(v.y), f2bf(v.z), f2bf(v.w) };
    *(ushort4*)(emb_bf + (size_t)k * C + lane * 4) = pk;
    float s = v.x * v.x + v.y * v.y + v.z * v.z + v.w * v.w;
#pragma unroll
    for (int off = 32; off > 0; off >>= 1) s += __shfl_down(s, off, 64);
    if (lane == 0) esq1[k] = 1.0f + s;
}

// --- kernel 2: single-wave blocks, Z in registers, E direct from L2 ---
// grid: 1024 blocks x 64 threads. Block = 64 tokens x all 1024 codes.
__global__ __launch_bounds__(64, 1) void vq_main(const float* __restrict__ z,
                                                 const float* __restrict__ emb,
                                                 const short* __restrict__ emb_bf,
                                                 const float* __restrict__ esq1,
                                                 float* __restrict__ out,
                                                 float* __restrict__ acc_loss) {
    // transpose buffer: [32 ch-blocks][64 tok][8 ch] bf16 = 32 KB
    __shared__ short Zs[32 * 512];

    const int L   = threadIdx.x;   // lane 0..63
    const int q   = L >> 4;        // quad
    const int l15 = L & 15;

    const int bidx = blockIdx.x;
    const int b    = bidx >> 4;           // batch
    const int hw0  = (bidx & 15) * 64;    // position tile base
    const float* zb = z + (size_t)b * C * HW + hw0;

    // ---- phase 1: transpose this wave's 64 tokens x 256 ch into LDS ----
    // lane = token; 4 channels per iteration, packed ds_write_b64
#pragma unroll 4
    for (int c = 0; c < C; c += 4) {
        float v0 = zb[(size_t)(c + 0) * HW + L];
        float v1 = zb[(size_t)(c + 1) * HW + L];
        float v2 = zb[(size_t)(c + 2) * HW + L];
        float v3 = zb[(size_t)(c + 3) * HW + L];
        ushort4 pk = { f2bf(v0), f2bf(v1), f2bf(v2), f2bf(v3) };
        *(ushort4*)&Zs[(c >> 3) * 512 + L * 8 + (c & 7)] = pk;
    }
    __syncthreads();

    // ---- phase 2: load B-fragments into registers (held for whole K loop) ----
    // zfrag[t][ks]: token = t*16 + l15, ch = ks*32 + q*8 + j
    bf16x8 zfrag[4][8];
#pragma unroll
    for (int t = 0; t < 4; ++t)
#pragma unroll
        for (int ks = 0; ks < 8; ++ks)
            zfrag[t][ks] = *(const bf16x8*)&Zs[(ks * 4 + q) * 512 + (t * 16 + l15) * 8];

    // ---- phase 3: K loop — no barriers, A-frags direct from L2 ----
    unsigned int best[4] = {0xFFFFFFFFu, 0xFFFFFFFFu, 0xFFFFFFFFu, 0xFFFFFFFFu};

    for (int k0 = 0; k0 < K; k0 += 64) {
        floatx4 acc[4][4];   // [m code tile][t token tile]
#pragma unroll
        for (int m = 0; m < 4; ++m)
#pragma unroll
            for (int t = 0; t < 4; ++t) acc[m][t] = (floatx4){0.f, 0.f, 0.f, 0.f};

#pragma unroll
        for (int ks = 0; ks < 8; ++ks) {
            U16 a[4];
#pragma unroll
            for (int m = 0; m < 4; ++m)
                a[m].u = *(const uint4*)(emb_bf + ((size_t)(k0 + m * 16 + l15) << 8) + ks * 32 + q * 8);
#pragma unroll
            for (int m = 0; m < 4; ++m)
#pragma unroll
                for (int t = 0; t < 4; ++t)
                    acc[m][t] = __builtin_amdgcn_mfma_f32_16x16x32_bf16(a[m].b, zfrag[t][ks], acc[m][t], 0, 0, 0);
        }

        // distances + packed argmin (d positive: bits monotone; low 10 bits = code)
#pragma unroll
        for (int m = 0; m < 4; ++m) {
            const float4 eq = *(const float4*)&esq1[k0 + m * 16 + q * 4];
            const float eqa[4] = {eq.x, eq.y, eq.z, eq.w};
#pragma unroll
            for (int r = 0; r < 4; ++r) {
                const unsigned int code = (unsigned int)(k0 + m * 16 + q * 4 + r);
#pragma unroll
                for (int t = 0; t < 4; ++t) {
                    float d = fmaf(-2.0f, acc[m][t][r], eqa[r]);
                    unsigned int u = (__float_as_uint(d) & 0xFFFFFC00u) | code;
                    best[t] = best[t] < u ? best[t] : u;
                }
            }
        }
    }

    // ---- phase 4: butterfly argmin across quads (all lanes get all results) ----
#pragma unroll
    for (int t = 0; t < 4; ++t) {
        unsigned int o = (unsigned int)__shfl_xor((int)best[t], 16, 64);
        best[t] = best[t] < o ? best[t] : o;
        o = (unsigned int)__shfl_xor((int)best[t], 32, 64);
        best[t] = best[t] < o ? best[t] : o;
    }
    // epilogue lane L handles token L = (L>>4)*16 + l15  ->  result best[L>>4]
    const int km = (int)(((q == 0) ? best[0] : (q == 1) ? best[1] : (q == 2) ? best[2] : best[3]) & 1023u);

    // ---- phase 5: gather code row (fp32), straight-through out, loss partials ----
    const float* erow = emb + (size_t)km * C;
    float s_sq = 0.0f, s_d = 0.0f;
    const size_t base = (size_t)b * C * HW + hw0 + L;
#pragma unroll 4
    for (int c = 0; c < C; c += 4) {
        float4 ev = *(const float4*)&erow[c];
        const float eva[4] = {ev.x, ev.y, ev.z, ev.w};
#pragma unroll
        for (int j = 0; j < 4; ++j) {
            float zv = z[base + (size_t)(c + j) * HW];
            float diff = eva[j] - zv;                      // z_q - z
            out[base + (size_t)(c + j) * HW] = zv + diff;  // straight-through fwd
            s_sq = fmaf(diff, diff, s_sq);
            s_d += diff;
        }
    }
#pragma unroll
    for (int off = 32; off > 0; off >>= 1) {
        s_sq += __shfl_down(s_sq, off, 64);
        s_d  += __shfl_down(s_d,  off, 64);
    }
    if (L == 0) {
        atomicAdd(&acc_loss[0], s_sq);
        atomicAdd(&acc_loss[1], s_d);
    }
}

// --- kernel 3: finalize scalar loss ---
__global__ void loss_kernel(const float* __restrict__ acc_loss,
                            float* __restrict__ out_loss) {
    out_loss[0] = acc_loss[0] * NTOT_INV + BETA * (acc_loss[1] * NTOT_INV);
}

extern "C" void kernel_launch(void* const* d_in, const int* in_sizes, int n_in,
                              void* d_out, int out_size, void* d_ws, size_t ws_size,
                              hipStream_t stream) {
    const float* z   = (const float*)d_in[0];   // [64,256,32,32]
    const float* emb = (const float*)d_in[1];   // [1024,256]
    float* out = (float*)d_out;                 // [16777216 z_q] + [1 loss]
    float* ws  = (float*)d_ws;
    float* acc  = ws;                               // 2 floats
    float* esq1 = ws + 64;                          // 1024 floats
    short* emb_bf = (short*)(ws + 64 + 1024);       // 1024*256 bf16 = 512 KB

    prep_kernel<<<dim3(K / 4), 256, 0, stream>>>(emb, emb_bf, esq1, acc);
    vq_main<<<dim3(1024), 64, 0, stream>>>(z, emb, emb_bf, esq1, out, acc);
    loss_kernel<<<1, 1, 0, stream>>>(acc, out + (size_t)B * C * HW);
}